// Round 3
// baseline (1351.019 us; speedup 1.0000x reference)
//
#include <hip/hip_runtime.h>
#include <hip/hip_bf16.h>

// LSTM (all-tanh gates), B=128, T=1024, IN=512, UNITS=128.
// Plan:
//   k_wt   : W [512,512] f32 -> Wt bf16 [n][k] (transposed, k-contiguous) in ws
//   k_gemm : xW = x @ W, bf16 MFMA 16x16x32, A loaded f32->cvt, out f32 (or bf16 if ws small)
//   k_scan : 128 workgroups (one per batch elem), 256 threads, quad-per-2-columns:
//            thread j: cp=j>>2, r=j&3 owns columns {cp, cp+64}, all 4 gates,
//            k in [32r,32r+32). Each 32-float h read feeds 8 FMAs/float
//            (2 cols x 4 gates) -> per-CU LDS-pipe traffic halved vs 1-col.
//            DPP transposed quad-reduce (gate r lands on lane r, 1 tanh/col),
//            DPP quad-broadcast, redundant c/h update, ONE barrier per step.

#define UNITS 128
#define IN_DIM 512
#define BATCH 128
#define SEQ 1024
#define GATES 512            // 4*UNITS
#define M_ROWS (BATCH * SEQ) // 131072

typedef __attribute__((ext_vector_type(8))) short short8;
typedef __attribute__((ext_vector_type(4))) float floatx4;
typedef __attribute__((ext_vector_type(4))) float fv4;
typedef __attribute__((ext_vector_type(2))) float fv2;

__device__ __forceinline__ unsigned short f2bf(float f) {
    unsigned int x = __builtin_bit_cast(unsigned int, f);
    unsigned int r = (x + 0x7fffu + ((x >> 16) & 1u)) >> 16; // RNE
    return (unsigned short)r;
}
__device__ __forceinline__ float bf2f(unsigned short u) {
    unsigned int x = ((unsigned int)u) << 16;
    return __builtin_bit_cast(float, x);
}
__device__ __forceinline__ unsigned int pack2(float lo, float hi) {
    return (unsigned int)f2bf(lo) | ((unsigned int)f2bf(hi) << 16);
}

// tanh(x) = 1 - 2/(exp2(2*log2e*x)+1); clamp keeps exp2 finite. ~1e-7 abs err.
__device__ __forceinline__ float fast_tanh(float x) {
    float y = fminf(34.6f, fmaxf(-34.6f, x * 2.88539008f));
    float e = __builtin_amdgcn_exp2f(y);
    return 1.0f - 2.0f * __builtin_amdgcn_rcpf(e + 1.0f);
}

// DPP helpers (quad_perm only -> works at any lane position, full exec).
template <int CTRL>
__device__ __forceinline__ float dppf(float x) {
    int xi = __builtin_bit_cast(int, x);
    int r = __builtin_amdgcn_update_dpp(0, xi, CTRL, 0xF, 0xF, true);
    return __builtin_bit_cast(float, r);
}
#define DPP_XOR1 0xB1 // [1,0,3,2]
#define DPP_XOR2 0x4E // [2,3,0,1]
#define DPP_BC0 0x00
#define DPP_BC1 0x55
#define DPP_BC2 0xAA
#define DPP_BC3 0xFF

__device__ __forceinline__ void pk_fma(fv2& acc, fv2 a, fv2 b) {
    asm("v_pk_fma_f32 %0, %1, %2, %0" : "+v"(acc) : "v"(a), "v"(b));
}

// ---------------- W transpose + convert: Wt[n][k] = bf16(W[k][n]) ----------
__global__ void k_wt(const float* __restrict__ W, unsigned short* __restrict__ Wt) {
    int idx = blockIdx.x * 256 + threadIdx.x; // 0..262143, coalesced writes
    int n = idx >> 9;
    int k = idx & 511;
    Wt[idx] = f2bf(W[k * 512 + n]);
}

// ---------------- GEMM: C[m][n] = sum_k A[m][k] * W[k][n] ------------------
// 128x128 block tile, BK=32, 256 threads (4 waves, 2x2 of 64x64), bf16 MFMA.
// LDS padded to 40 elems/row (+16B) -> 2-way-max bank aliasing, 16B aligned rows.
template <bool XWF32>
__global__ void __launch_bounds__(256, 2)
k_gemm(const float* __restrict__ A, const unsigned short* __restrict__ Bt,
       void* __restrict__ Cout) {
    __shared__ __align__(16) unsigned short As[128 * 40];
    __shared__ __align__(16) unsigned short Bs[128 * 40];
    const int tid = threadIdx.x;
    const int m0 = blockIdx.y << 7;
    const int n0 = blockIdx.x << 7;
    const int l = tid & 63;
    const int w = tid >> 6;
    const int wr = (w >> 1) << 6; // wave row offset within tile
    const int wc = (w & 1) << 6;  // wave col offset
    const int lrow = l & 15;      // A/B fragment: own-index = lane%16
    const int lq = l >> 4;        // k-quarter: k = lq*8 + j

    floatx4 acc[4][4] = {};

    // staging map: thread -> (row srow, 16-elem half soff)
    const int srow = tid >> 1;
    const int soff = (tid & 1) << 4;
    const float* ap = A + (size_t)(m0 + srow) * 512 + soff;
    const unsigned short* bp = Bt + (size_t)(n0 + srow) * 512 + soff;
    unsigned short* as = &As[srow * 40 + soff];
    unsigned short* bs = &Bs[srow * 40 + soff];

    for (int k0 = 0; k0 < 512; k0 += 32) {
        float4 a0 = *(const float4*)(ap + k0);
        float4 a1 = *(const float4*)(ap + k0 + 4);
        float4 a2 = *(const float4*)(ap + k0 + 8);
        float4 a3 = *(const float4*)(ap + k0 + 12);
        uint4 b0 = *(const uint4*)(bp + k0);
        uint4 b1 = *(const uint4*)(bp + k0 + 8);
        __syncthreads(); // prev iteration's readers done before overwrite
        uint4 pa0, pa1;
        pa0.x = pack2(a0.x, a0.y); pa0.y = pack2(a0.z, a0.w);
        pa0.z = pack2(a1.x, a1.y); pa0.w = pack2(a1.z, a1.w);
        pa1.x = pack2(a2.x, a2.y); pa1.y = pack2(a2.z, a2.w);
        pa1.z = pack2(a3.x, a3.y); pa1.w = pack2(a3.z, a3.w);
        *(uint4*)as = pa0;
        *(uint4*)(as + 8) = pa1;
        *(uint4*)bs = b0;
        *(uint4*)(bs + 8) = b1;
        __syncthreads();
        short8 af[4], bfv[4];
#pragma unroll
        for (int mi = 0; mi < 4; ++mi)
            af[mi] = *(const short8*)&As[(wr + mi * 16 + lrow) * 40 + lq * 8];
#pragma unroll
        for (int ni = 0; ni < 4; ++ni)
            bfv[ni] = *(const short8*)&Bs[(wc + ni * 16 + lrow) * 40 + lq * 8];
#pragma unroll
        for (int mi = 0; mi < 4; ++mi)
#pragma unroll
            for (int ni = 0; ni < 4; ++ni)
                acc[mi][ni] = __builtin_amdgcn_mfma_f32_16x16x32_bf16(
                    af[mi], bfv[ni], acc[mi][ni], 0, 0, 0);
    }
    // epilogue: C/D layout col=lane&15, row=(lane>>4)*4+r
#pragma unroll
    for (int mi = 0; mi < 4; ++mi) {
#pragma unroll
        for (int ni = 0; ni < 4; ++ni) {
            int row = m0 + wr + mi * 16 + lq * 4;
            int col = n0 + wc + ni * 16 + lrow;
            if (XWF32) {
                float* Cf = (float*)Cout;
#pragma unroll
                for (int r = 0; r < 4; ++r)
                    Cf[(size_t)(row + r) * 512 + col] = acc[mi][ni][r];
            } else {
                unsigned short* Cb = (unsigned short*)Cout;
#pragma unroll
                for (int r = 0; r < 4; ++r)
                    Cb[(size_t)(row + r) * 512 + col] = f2bf(acc[mi][ni][r]);
            }
        }
    }
}

// ---------------- recurrent scan: one workgroup per batch element ----------
// 256 threads = 64 quads. Thread j: cp=j>>2 (0..63), r=j&3. Owns columns
// {cp, cp+64}, all 4 gates, k-quarter [32r,32r+32). U slices = 256 floats in
// VGPRs (launch_bounds(256,1): cap 512 VGPR, 1 wave/SIMD — fine since only
// one block ever resides per CU with 128 blocks on 256 CUs).
// Per step:
//   8x ds_read_b128 (h, 32 floats, shared by BOTH columns -> 8 FMA per float)
//   128 v_pk_fma_f32 -> DPP transposed quad-reduce per column (lane r ends
//   with gate r) -> 1 tanh per column -> 4 DPP broadcasts per column ->
//   redundant c/h update (c in regs) -> r==0 writes 2 h values -> ONE barrier.
template <bool XWF32>
__global__ void __launch_bounds__(256, 1)
k_scan(const void* __restrict__ xwv, const float* __restrict__ U,
       const float* __restrict__ bias, float* __restrict__ out) {
    __shared__ __align__(16) float hbuf[2 * 160]; // [buf][quarter*40 + (m&31)]
    const int j = threadIdx.x;
    const int bb = blockIdx.x;
    const int cp = j >> 2; // column pair: owns cp and cp+64
    const int r = j & 3;   // k-quarter AND own-gate index

    // U slices, packed along k: u2[col][g][i] =
    //   (U[r*32+2i][g*128+m], U[r*32+2i+1][g*128+m]),  m = cp or cp+64
    fv2 u2[2][4][16];
#pragma unroll
    for (int i = 0; i < 16; ++i) {
        const float* Up0 = U + (size_t)(r * 32 + 2 * i) * 512;
        const float* Up1 = Up0 + 512;
#pragma unroll
        for (int g = 0; g < 4; ++g) {
            u2[0][g][i] = (fv2){Up0[g * 128 + cp], Up1[g * 128 + cp]};
            u2[1][g][i] = (fv2){Up0[g * 128 + cp + 64], Up1[g * 128 + cp + 64]};
        }
    }
    const float bA = bias[r * 128 + cp];      // own-gate bias, column cp
    const float bB = bias[r * 128 + cp + 64]; // own-gate bias, column cp+64
    const int p = r & 1;
    const int q = (r >> 1) & 1;

    if (j < 160) hbuf[j] = 0.0f; // h0 = 0 (buffer 0, incl. pad)
    __syncthreads();

    // per-lane xw streams: own gate r, columns cp and cp+64
    const float* xwfA = (const float*)xwv + (size_t)bb * SEQ * 512 + r * 128 + cp;
    const unsigned short* xwbA =
        (const unsigned short*)xwv + (size_t)bb * SEQ * 512 + r * 128 + cp;

    float cA = 0.0f, cB = 0.0f, hA = 0.0f, hB = 0.0f;
    float xbA = (XWF32 ? xwfA[0] : bf2f(xwbA[0])) + bA;
    float xbB = (XWF32 ? xwfA[64] : bf2f(xwbA[64])) + bB;
    for (int t = 0; t < SEQ; ++t) {
        float xwA_n = 0.0f, xwB_n = 0.0f;
        if (t + 1 < SEQ) {
            if (XWF32) {
                xwA_n = xwfA[(size_t)(t + 1) * 512];
                xwB_n = xwfA[(size_t)(t + 1) * 512 + 64];
            } else {
                xwA_n = bf2f(xwbA[(size_t)(t + 1) * 512]);
                xwB_n = bf2f(xwbA[(size_t)(t + 1) * 512 + 64]);
            }
        }

        fv2 aA0 = {0.f, 0.f}, aA1 = {0.f, 0.f}, aA2 = {0.f, 0.f}, aA3 = {0.f, 0.f};
        fv2 aB0 = {0.f, 0.f}, aB1 = {0.f, 0.f}, aB2 = {0.f, 0.f}, aB3 = {0.f, 0.f};
        const fv4* h4 =
            (const fv4*)(hbuf + (t & 1) * 160 + r * 40); // this lane's k-quarter
#pragma unroll
        for (int i = 0; i < 8; ++i) {
            fv4 hv = h4[i];
            fv2 hl = hv.lo;
            fv2 hh = hv.hi;
            pk_fma(aA0, hl, u2[0][0][2 * i]);
            pk_fma(aA1, hl, u2[0][1][2 * i]);
            pk_fma(aA2, hl, u2[0][2][2 * i]);
            pk_fma(aA3, hl, u2[0][3][2 * i]);
            pk_fma(aB0, hl, u2[1][0][2 * i]);
            pk_fma(aB1, hl, u2[1][1][2 * i]);
            pk_fma(aB2, hl, u2[1][2][2 * i]);
            pk_fma(aB3, hl, u2[1][3][2 * i]);
            pk_fma(aA0, hh, u2[0][0][2 * i + 1]);
            pk_fma(aA1, hh, u2[0][1][2 * i + 1]);
            pk_fma(aA2, hh, u2[0][2][2 * i + 1]);
            pk_fma(aA3, hh, u2[0][3][2 * i + 1]);
            pk_fma(aB0, hh, u2[1][0][2 * i + 1]);
            pk_fma(aB1, hh, u2[1][1][2 * i + 1]);
            pk_fma(aB2, hh, u2[1][2][2 * i + 1]);
            pk_fma(aB3, hh, u2[1][3][2 * i + 1]);
        }
        float sA0 = aA0.x + aA0.y, sA1 = aA1.x + aA1.y;
        float sA2 = aA2.x + aA2.y, sA3 = aA3.x + aA3.y;
        float sB0 = aB0.x + aB0.y, sB1 = aB1.x + aB1.y;
        float sB2 = aB2.x + aB2.y, sB3 = aB3.x + aB3.y;

        // transposed quad-reduce: lane r ends with sigma = full dot of gate r
        float vaA = p ? sA1 : sA0, oaA = p ? sA0 : sA1;
        float vbA = p ? sA3 : sA2, obA = p ? sA2 : sA3;
        float vaB = p ? sB1 : sB0, oaB = p ? sB0 : sB1;
        float vbB = p ? sB3 : sB2, obB = p ? sB2 : sB3;
        float a01A = vaA + dppf<DPP_XOR1>(oaA);
        float a23A = vbA + dppf<DPP_XOR1>(obA);
        float a01B = vaB + dppf<DPP_XOR1>(oaB);
        float a23B = vbB + dppf<DPP_XOR1>(obB);
        float vvA = q ? a23A : a01A, ooA = q ? a01A : a23A;
        float vvB = q ? a23B : a01B, ooB = q ? a01B : a23B;
        float sigA = vvA + dppf<DPP_XOR2>(ooA);
        float sigB = vvB + dppf<DPP_XOR2>(ooB);

        float tgA = fast_tanh(sigA + xbA); // own gate, all-tanh variant
        float tgB = fast_tanh(sigB + xbB);

        // quad broadcast of the four gate activations (Keras order i,f,g,o)
        float giA = dppf<DPP_BC0>(tgA), gfA = dppf<DPP_BC1>(tgA);
        float ggA = dppf<DPP_BC2>(tgA), goA = dppf<DPP_BC3>(tgA);
        float giB = dppf<DPP_BC0>(tgB), gfB = dppf<DPP_BC1>(tgB);
        float ggB = dppf<DPP_BC2>(tgB), goB = dppf<DPP_BC3>(tgB);
        cA = fmaf(gfA, cA, giA * ggA);
        cB = fmaf(gfB, cB, giB * ggB);
        hA = goA * fast_tanh(cA);
        hB = goB * fast_tanh(cB);

        if (r == 0) {
            float* nb = hbuf + ((t + 1) & 1) * 160;
            nb[(cp >> 5) * 40 + (cp & 31)] = hA;
            nb[((cp >> 5) + 2) * 40 + (cp & 31)] = hB;
        }
        __syncthreads(); // write of buf[t+1] visible before next step's reads
        xbA = xwA_n + bA;
        xbB = xwB_n + bB;
    }
    if (r == 0) {
        out[bb * UNITS + cp] = hA;
        out[bb * UNITS + cp + 64] = hB;
    }
}

// ---------------------------------------------------------------------------
extern "C" void kernel_launch(void* const* d_in, const int* in_sizes, int n_in,
                              void* d_out, int out_size, void* d_ws, size_t ws_size,
                              hipStream_t stream) {
    const float* x = (const float*)d_in[0]; // [128,1024,512]
    const float* W = (const float*)d_in[1]; // [512,512]
    const float* U = (const float*)d_in[2]; // [128,512]
    const float* b = (const float*)d_in[3]; // [512]
    float* out = (float*)d_out;             // [128,128]

    char* ws = (char*)d_ws;
    const size_t WT_BYTES = (size_t)512 * 512 * 2; // 512 KB
    unsigned short* Wt = (unsigned short*)ws;
    void* xw = (void*)(ws + WT_BYTES);
    const size_t XW_F32_BYTES = (size_t)M_ROWS * 512 * 4; // 256 MB
    const bool f32path = (ws_size >= WT_BYTES + XW_F32_BYTES);

    k_wt<<<dim3(1024), dim3(256), 0, stream>>>(W, Wt);

    dim3 ggrid(4, 1024); // N-tiles x M-tiles
    if (f32path) {
        k_gemm<true><<<ggrid, dim3(256), 0, stream>>>(x, Wt, xw);
        k_scan<true><<<dim3(128), dim3(256), 0, stream>>>(xw, U, b, out);
    } else {
        k_gemm<false><<<ggrid, dim3(256), 0, stream>>>(x, Wt, xw);
        k_scan<false><<<dim3(128), dim3(256), 0, stream>>>(xw, U, b, out);
    }
}

// Round 11
// 1123.171 us; speedup vs baseline: 1.2029x; 1.2029x over previous
//
#include <hip/hip_runtime.h>
#include <hip/hip_bf16.h>

// LSTM (all-tanh gates), B=128, T=1024, IN=512, UNITS=128.
// Plan:
//   k_wt   : W [512,512] f32 -> Wt bf16 [n][k] (transposed, k-contiguous) in ws
//   k_gemm : xW = x @ W, bf16 MFMA 16x16x32, out f32 (or bf16 if ws small)
//   k_scan : 128 workgroups (one per batch elem), 512 threads (8 waves,
//            2/SIMD for TLP). Thread j: e=j&7 owns k-slice [16e,16e+16),
//            cg=j>>3 owns columns {cg,cg+64} x 4 gates = 8 partial dots.
//            4x ds_read_b128 (8-way broadcast, bank-disjoint via 20-float
//            chunk padding), 64 v_pk_fma_f32, 8-lane transposed butterfly
//            over hop masks {1,2,7} (quad_perm xor1/xor2 + row_half_mirror).
//            row_half_mirror is lane XOR-7 (NOT xor-4!), so selection bits
//            are f1=b0^b2, f2=b1^b2, f3=b2 -> pair P(e)=f1+2f2+4f3 lands on
//            lane e (P=e for e<4, P=11-e for e>=4). ONE tanh/thread ->
//            quad broadcast (reversed ctrl on upper quads) -> redundant c/h
//            update -> ONE barrier per step.

#define UNITS 128
#define IN_DIM 512
#define BATCH 128
#define SEQ 1024
#define GATES 512            // 4*UNITS
#define M_ROWS (BATCH * SEQ) // 131072

typedef __attribute__((ext_vector_type(8))) short short8;
typedef __attribute__((ext_vector_type(4))) float floatx4;
typedef __attribute__((ext_vector_type(4))) float fv4;
typedef __attribute__((ext_vector_type(2))) float fv2;

__device__ __forceinline__ unsigned short f2bf(float f) {
    unsigned int x = __builtin_bit_cast(unsigned int, f);
    unsigned int r = (x + 0x7fffu + ((x >> 16) & 1u)) >> 16; // RNE
    return (unsigned short)r;
}
__device__ __forceinline__ float bf2f(unsigned short u) {
    unsigned int x = ((unsigned int)u) << 16;
    return __builtin_bit_cast(float, x);
}
__device__ __forceinline__ unsigned int pack2(float lo, float hi) {
    return (unsigned int)f2bf(lo) | ((unsigned int)f2bf(hi) << 16);
}

// tanh(x) = 1 - 2/(exp2(2*log2e*x)+1); clamp keeps exp2 finite. ~1e-7 abs err.
__device__ __forceinline__ float fast_tanh(float x) {
    float y = fminf(34.6f, fmaxf(-34.6f, x * 2.88539008f));
    float e = __builtin_amdgcn_exp2f(y);
    return 1.0f - 2.0f * __builtin_amdgcn_rcpf(e + 1.0f);
}

// DPP helpers (quad_perm / row_half_mirror -> row-local, full exec).
template <int CTRL>
__device__ __forceinline__ float dppf(float x) {
    int xi = __builtin_bit_cast(int, x);
    int r = __builtin_amdgcn_update_dpp(0, xi, CTRL, 0xF, 0xF, true);
    return __builtin_bit_cast(float, r);
}
#define DPP_XOR1 0xB1  // quad_perm [1,0,3,2]
#define DPP_XOR2 0x4E  // quad_perm [2,3,0,1]
#define DPP_HMIR 0x141 // row_half_mirror: lane i -> 7-i within 8-lane group (XOR 7)
#define DPP_BC0 0x00
#define DPP_BC1 0x55
#define DPP_BC2 0xAA
#define DPP_BC3 0xFF

__device__ __forceinline__ void pk_fma(fv2& acc, fv2 a, fv2 b) {
    asm("v_pk_fma_f32 %0, %1, %2, %0" : "+v"(acc) : "v"(a), "v"(b));
}

// ---------------- W transpose + convert: Wt[n][k] = bf16(W[k][n]) ----------
__global__ void k_wt(const float* __restrict__ W, unsigned short* __restrict__ Wt) {
    int idx = blockIdx.x * 256 + threadIdx.x; // 0..262143, coalesced writes
    int n = idx >> 9;
    int k = idx & 511;
    Wt[idx] = f2bf(W[k * 512 + n]);
}

// ---------------- GEMM: C[m][n] = sum_k A[m][k] * W[k][n] ------------------
// 128x128 block tile, BK=32, 256 threads (4 waves, 2x2 of 64x64), bf16 MFMA.
// LDS padded to 40 elems/row (+16B) -> 2-way-max bank aliasing, 16B aligned rows.
template <bool XWF32>
__global__ void __launch_bounds__(256, 2)
k_gemm(const float* __restrict__ A, const unsigned short* __restrict__ Bt,
       void* __restrict__ Cout) {
    __shared__ __align__(16) unsigned short As[128 * 40];
    __shared__ __align__(16) unsigned short Bs[128 * 40];
    const int tid = threadIdx.x;
    const int m0 = blockIdx.y << 7;
    const int n0 = blockIdx.x << 7;
    const int l = tid & 63;
    const int w = tid >> 6;
    const int wr = (w >> 1) << 6; // wave row offset within tile
    const int wc = (w & 1) << 6;  // wave col offset
    const int lrow = l & 15;      // A/B fragment: own-index = lane%16
    const int lq = l >> 4;        // k-quarter: k = lq*8 + j

    floatx4 acc[4][4] = {};

    // staging map: thread -> (row srow, 16-elem half soff)
    const int srow = tid >> 1;
    const int soff = (tid & 1) << 4;
    const float* ap = A + (size_t)(m0 + srow) * 512 + soff;
    const unsigned short* bp = Bt + (size_t)(n0 + srow) * 512 + soff;
    unsigned short* as = &As[srow * 40 + soff];
    unsigned short* bs = &Bs[srow * 40 + soff];

    for (int k0 = 0; k0 < 512; k0 += 32) {
        float4 a0 = *(const float4*)(ap + k0);
        float4 a1 = *(const float4*)(ap + k0 + 4);
        float4 a2 = *(const float4*)(ap + k0 + 8);
        float4 a3 = *(const float4*)(ap + k0 + 12);
        uint4 b0 = *(const uint4*)(bp + k0);
        uint4 b1 = *(const uint4*)(bp + k0 + 8);
        __syncthreads(); // prev iteration's readers done before overwrite
        uint4 pa0, pa1;
        pa0.x = pack2(a0.x, a0.y); pa0.y = pack2(a0.z, a0.w);
        pa0.z = pack2(a1.x, a1.y); pa0.w = pack2(a1.z, a1.w);
        pa1.x = pack2(a2.x, a2.y); pa1.y = pack2(a2.z, a2.w);
        pa1.z = pack2(a3.x, a3.y); pa1.w = pack2(a3.z, a3.w);
        *(uint4*)as = pa0;
        *(uint4*)(as + 8) = pa1;
        *(uint4*)bs = b0;
        *(uint4*)(bs + 8) = b1;
        __syncthreads();
        short8 af[4], bfv[4];
#pragma unroll
        for (int mi = 0; mi < 4; ++mi)
            af[mi] = *(const short8*)&As[(wr + mi * 16 + lrow) * 40 + lq * 8];
#pragma unroll
        for (int ni = 0; ni < 4; ++ni)
            bfv[ni] = *(const short8*)&Bs[(wc + ni * 16 + lrow) * 40 + lq * 8];
#pragma unroll
        for (int mi = 0; mi < 4; ++mi)
#pragma unroll
            for (int ni = 0; ni < 4; ++ni)
                acc[mi][ni] = __builtin_amdgcn_mfma_f32_16x16x32_bf16(
                    af[mi], bfv[ni], acc[mi][ni], 0, 0, 0);
    }
    // epilogue: C/D layout col=lane&15, row=(lane>>4)*4+r
#pragma unroll
    for (int mi = 0; mi < 4; ++mi) {
#pragma unroll
        for (int ni = 0; ni < 4; ++ni) {
            int row = m0 + wr + mi * 16 + lq * 4;
            int col = n0 + wc + ni * 16 + lrow;
            if (XWF32) {
                float* Cf = (float*)Cout;
#pragma unroll
                for (int r = 0; r < 4; ++r)
                    Cf[(size_t)(row + r) * 512 + col] = acc[mi][ni][r];
            } else {
                unsigned short* Cb = (unsigned short*)Cout;
#pragma unroll
                for (int r = 0; r < 4; ++r)
                    Cb[(size_t)(row + r) * 512 + col] = f2bf(acc[mi][ni][r]);
            }
        }
    }
}

// ---------------- recurrent scan: one workgroup per batch element ----------
// 512 threads. Thread j: e=j&7 (k-slice [16e,16e+16)), cg=j>>3 (cols cg,cg+64).
// 8 partial dots/thread (2 cols x 4 gates) over 16 h-floats; U slice = 128
// floats in registers. h lives in LDS chunks of 20 floats (16 data + 4 pad)
// so the 8 concurrent b128 read groups cover all 32 banks exactly once.
template <bool XWF32>
__global__ void __launch_bounds__(512, 1)
k_scan(const void* __restrict__ xwv, const float* __restrict__ U,
       const float* __restrict__ bias, float* __restrict__ out) {
    __shared__ __align__(16) float hbuf[2 * 160]; // [buf][chunk e: e*20 + slot]
    const int j = threadIdx.x;
    const int bb = blockIdx.x;
    const int e = j & 7;   // k-slice index
    const int cg = j >> 3; // column group: owns cg and cg+64

    // u2[p][i]: pair p = (gate g=p&3, colsel s=p>>2 -> col cg+64s),
    //           i-th fv2 = (U[16e+2i][g*128+col], U[16e+2i+1][g*128+col])
    fv2 u2[8][8];
#pragma unroll
    for (int i = 0; i < 8; ++i) {
        const float* Up0 = U + (size_t)(16 * e + 2 * i) * 512;
        const float* Up1 = Up0 + 512;
#pragma unroll
        for (int g = 0; g < 4; ++g) {
            u2[g][i] = (fv2){Up0[g * 128 + cg], Up1[g * 128 + cg]};
            u2[4 + g][i] = (fv2){Up0[g * 128 + cg + 64], Up1[g * 128 + cg + 64]};
        }
    }
    // butterfly selection bits (hop masks {1,2,7}; see header comment)
    const int f1 = (e ^ (e >> 2)) & 1;        // b0^b2
    const int f2 = ((e >> 1) ^ (e >> 2)) & 1; // b1^b2
    const int f3 = (e >> 2) & 1;              // b2
    const int myg = f1 + 2 * f2;              // own gate after reduce
    const int mycol = cg + (f3 << 6);         // own column after reduce
    const int gidx = myg * 128 + mycol;       // own (gate,col) flat index
    const float bj = bias[gidx];

    if (j < 320) hbuf[j] = 0.0f; // both buffers (incl. pads)
    __syncthreads();

    // per-lane xw stream: own gate/col only -> exactly 2KB/step/block total
    const float* xwf = (const float*)xwv + (size_t)bb * SEQ * 512 + gidx;
    const unsigned short* xwb =
        (const unsigned short*)xwv + (size_t)bb * SEQ * 512 + gidx;

    float c = 0.0f, hval = 0.0f;
    float xb_cur = (XWF32 ? xwf[0] : bf2f(xwb[0])) + bj;
    const int wslot = ((mycol >> 4) * 20) + (mycol & 15); // h write addr (e==0||e==4)

    for (int t = 0; t < SEQ; ++t) {
        float xw_next = 0.0f;
        if (t + 1 < SEQ)
            xw_next = XWF32 ? xwf[(size_t)(t + 1) * 512]
                            : bf2f(xwb[(size_t)(t + 1) * 512]);

        fv2 a0 = {0.f, 0.f}, a1 = {0.f, 0.f}, a2 = {0.f, 0.f}, a3 = {0.f, 0.f};
        fv2 a4 = {0.f, 0.f}, a5 = {0.f, 0.f}, a6 = {0.f, 0.f}, a7 = {0.f, 0.f};
        const fv4* h4 = (const fv4*)(hbuf + (t & 1) * 160 + e * 20);
#pragma unroll
        for (int i = 0; i < 4; ++i) {
            fv4 hv = h4[i];
            fv2 hl = hv.lo;
            fv2 hh = hv.hi;
            pk_fma(a0, hl, u2[0][2 * i]);
            pk_fma(a1, hl, u2[1][2 * i]);
            pk_fma(a2, hl, u2[2][2 * i]);
            pk_fma(a3, hl, u2[3][2 * i]);
            pk_fma(a4, hl, u2[4][2 * i]);
            pk_fma(a5, hl, u2[5][2 * i]);
            pk_fma(a6, hl, u2[6][2 * i]);
            pk_fma(a7, hl, u2[7][2 * i]);
            pk_fma(a0, hh, u2[0][2 * i + 1]);
            pk_fma(a1, hh, u2[1][2 * i + 1]);
            pk_fma(a2, hh, u2[2][2 * i + 1]);
            pk_fma(a3, hh, u2[3][2 * i + 1]);
            pk_fma(a4, hh, u2[4][2 * i + 1]);
            pk_fma(a5, hh, u2[5][2 * i + 1]);
            pk_fma(a6, hh, u2[6][2 * i + 1]);
            pk_fma(a7, hh, u2[7][2 * i + 1]);
        }
        float s0 = a0.x + a0.y, s1 = a1.x + a1.y;
        float s2 = a2.x + a2.y, s3 = a3.x + a3.y;
        float s4 = a4.x + a4.y, s5 = a5.x + a5.y;
        float s6 = a6.x + a6.y, s7 = a7.x + a7.y;

        // 8-lane transposed butterfly over hop masks {1,2,7}.
        // Hop1 (xor1, select f1): t_q holds pair-bit0=f1 over lane pair.
        float t0 = (f1 ? s1 : s0) + dppf<DPP_XOR1>(f1 ? s0 : s1);
        float t1 = (f1 ? s3 : s2) + dppf<DPP_XOR1>(f1 ? s2 : s3);
        float t2 = (f1 ? s5 : s4) + dppf<DPP_XOR1>(f1 ? s4 : s5);
        float t3 = (f1 ? s7 : s6) + dppf<DPP_XOR1>(f1 ? s6 : s7);
        // Hop2 (xor2, select f2): v holds pair bits (f1,f2) over quad.
        float v0 = (f2 ? t1 : t0) + dppf<DPP_XOR2>(f2 ? t0 : t1);
        float v1 = (f2 ? t3 : t2) + dppf<DPP_XOR2>(f2 ? t2 : t3);
        // Hop3 (xor7 = row_half_mirror, select f3): full pair P=f1+2f2+4f3.
        // f1,f2 are invariant under xor7 (both involve b2), so the remote
        // half belongs to the SAME pair.
        float sig = (f3 ? v1 : v0) + dppf<DPP_HMIR>(f3 ? v0 : v1);

        float tg = fast_tanh(sig + xb_cur); // own gate (all-tanh variant)

        // quad broadcast: lower quads (e<4) hold gates in order i,f,g,o at
        // quad-lanes 0..3; upper quads hold them REVERSED (P=11-e): o,g,f,i.
        float q0 = dppf<DPP_BC0>(tg);
        float q1 = dppf<DPP_BC1>(tg);
        float q2 = dppf<DPP_BC2>(tg);
        float q3 = dppf<DPP_BC3>(tg);
        const bool hi = f3;
        float gi = hi ? q3 : q0;
        float gf = hi ? q2 : q1;
        float gg = hi ? q1 : q2;
        float go = hi ? q0 : q3;
        c = fmaf(gf, c, gi * gg);
        hval = go * fast_tanh(c);

        if ((e & 3) == 0) // e==0 writes col cg, e==4 writes col cg+64
            hbuf[((t + 1) & 1) * 160 + wslot] = hval;
        __syncthreads(); // buf[t+1] visible before next step's reads
        xb_cur = xw_next + bj;
    }
    if ((e & 3) == 0) out[bb * UNITS + mycol] = hval;
}

// ---------------------------------------------------------------------------
extern "C" void kernel_launch(void* const* d_in, const int* in_sizes, int n_in,
                              void* d_out, int out_size, void* d_ws, size_t ws_size,
                              hipStream_t stream) {
    const float* x = (const float*)d_in[0]; // [128,1024,512]
    const float* W = (const float*)d_in[1]; // [512,512]
    const float* U = (const float*)d_in[2]; // [128,512]
    const float* b = (const float*)d_in[3]; // [512]
    float* out = (float*)d_out;             // [128,128]

    char* ws = (char*)d_ws;
    const size_t WT_BYTES = (size_t)512 * 512 * 2; // 512 KB
    unsigned short* Wt = (unsigned short*)ws;
    void* xw = (void*)(ws + WT_BYTES);
    const size_t XW_F32_BYTES = (size_t)M_ROWS * 512 * 4; // 256 MB
    const bool f32path = (ws_size >= WT_BYTES + XW_F32_BYTES);

    k_wt<<<dim3(1024), dim3(256), 0, stream>>>(W, Wt);

    dim3 ggrid(4, 1024); // N-tiles x M-tiles
    if (f32path) {
        k_gemm<true><<<ggrid, dim3(256), 0, stream>>>(x, Wt, xw);
        k_scan<true><<<dim3(128), dim3(512), 0, stream>>>(xw, U, b, out);
    } else {
        k_gemm<false><<<ggrid, dim3(256), 0, stream>>>(x, Wt, xw);
        k_scan<false><<<dim3(128), dim3(512), 0, stream>>>(xw, U, b, out);
    }
}